// Round 4
// baseline (647.774 us; speedup 1.0000x reference)
//
#include <hip/hip_runtime.h>
#include <stdint.h>

typedef __bf16 bf16x8_t __attribute__((ext_vector_type(8)));
typedef float f32x4_t __attribute__((ext_vector_type(4)));
typedef uint16_t u16x8_t __attribute__((ext_vector_type(8)));
typedef uint16_t u16x4_t __attribute__((ext_vector_type(4)));

#define MFMA16(a, b, c) __builtin_amdgcn_mfma_f32_16x16x32_bf16((a), (b), (c), 0, 0, 0)

__device__ __forceinline__ void gll16(const void* g, void* l) {
  typedef const __attribute__((address_space(1))) void* gp1_t;
  typedef __attribute__((address_space(3))) void* lp3_t;
  __builtin_amdgcn_global_load_lds((gp1_t)(uintptr_t)g,
                                   (lp3_t)(uint32_t)(uintptr_t)l, 16, 0, 0);
}

__device__ __forceinline__ uint16_t f2bf(float f) {
  uint32_t u = __float_as_uint(f);
  u += 0x7fffu + ((u >> 16) & 1u);
  return (uint16_t)(u >> 16);
}

// ----------------------------- fp32 -> bf16 convert (optional scale) -----------------------------
__global__ __launch_bounds__(256) void cvt_kernel(const float* __restrict__ in,
                                                  uint16_t* __restrict__ out, int n8,
                                                  float scale) {
  int i = blockIdx.x * 256 + threadIdx.x;
  if (i >= n8) return;
  const float4* p = (const float4*)in;
  float4 a = p[2 * i], b = p[2 * i + 1];
  u16x8_t v;
  v[0] = f2bf(a.x * scale); v[1] = f2bf(a.y * scale);
  v[2] = f2bf(a.z * scale); v[3] = f2bf(a.w * scale);
  v[4] = f2bf(b.x * scale); v[5] = f2bf(b.y * scale);
  v[6] = f2bf(b.z * scale); v[7] = f2bf(b.w * scale);
  ((u16x8_t*)out)[i] = v;
}

// ----------------------------- bf16 NT GEMM: C = A * Bw^T + alpha*bias -----------------------------
// MODE 0: fp32 row-major out. MODE 1: bf16 row-major out. MODE 2: bf16 V^T per-head out
// ([b][h][d][t] with col = h*64+d, row = b*2048+t).
template <int MODE>
__global__ __launch_bounds__(256) void gemm_bt_kernel(const uint16_t* __restrict__ A,
                                                      const uint16_t* __restrict__ Bw,
                                                      const float* __restrict__ bias,
                                                      void* __restrict__ C, float alpha) {
  constexpr int K = 1024, N = 1024;
  __shared__ uint16_t As[128 * 64];
  __shared__ uint16_t Bs[128 * 64];
  char* AsB = (char*)As;
  char* BsB = (char*)Bs;
  const int tid = threadIdx.x;
  const int w = tid >> 6, l = tid & 63;
  const int wr = w >> 1, wc = w & 1;
  const int lrow = l & 15, g = l >> 4;
  const int bm0 = blockIdx.y * 128, bn0 = blockIdx.x * 128;
  const int srow = l >> 3;
  const int scb = ((l & 7) ^ srow) << 4;
  const char* Ab = (const char*)A;
  const char* Bb = (const char*)Bw;
  f32x4_t acc[4][4] = {};

  for (int it = 0; it < K / 64; ++it) {
    const int k0 = it * 64;
    __syncthreads();
#pragma unroll
    for (int s = 0; s < 4; ++s) {
      const int rbase = s * 32 + w * 8;
      gll16(Ab + (size_t)(bm0 + rbase + srow) * (K * 2) + k0 * 2 + scb, AsB + rbase * 128);
      gll16(Bb + (size_t)(bn0 + rbase + srow) * (K * 2) + k0 * 2 + scb, BsB + rbase * 128);
    }
    asm volatile("s_waitcnt vmcnt(0)" ::: "memory");
    __syncthreads();
#pragma unroll
    for (int kk = 0; kk < 2; ++kk) {
      bf16x8_t af[4], bfr[4];
#pragma unroll
      for (int f = 0; f < 4; ++f) {
        const int ar = wr * 64 + f * 16 + lrow;
        af[f] = *(const bf16x8_t*)(AsB + ar * 128 + ((kk * 64 + g * 16) ^ ((ar & 7) << 4)));
        const int br = wc * 64 + f * 16 + lrow;
        bfr[f] = *(const bf16x8_t*)(BsB + br * 128 + ((kk * 64 + g * 16) ^ ((br & 7) << 4)));
      }
#pragma unroll
      for (int fm = 0; fm < 4; ++fm)
#pragma unroll
        for (int fn = 0; fn < 4; ++fn)
          acc[fm][fn] = MFMA16(af[fm], bfr[fn], acc[fm][fn]);
    }
  }
  // epilogue: C/D layout col = lane&15, row = (lane>>4)*4 + reg
#pragma unroll
  for (int fn = 0; fn < 4; ++fn) {
    const int col = bn0 + wc * 64 + fn * 16 + lrow;
    const float bv = bias[col] * alpha;
#pragma unroll
    for (int fm = 0; fm < 4; ++fm) {
      const int row0 = bm0 + wr * 64 + fm * 16 + g * 4;
      if constexpr (MODE == 2) {
        const int b = row0 >> 11, t = row0 & 2047;
        u16x4_t pv;
#pragma unroll
        for (int r = 0; r < 4; ++r) pv[r] = f2bf(acc[fm][fn][r] + bv);
        const size_t idx = ((size_t)((b << 4) + (col >> 6)) * 64 + (col & 63)) * 2048 + t;
        *(u16x4_t*)((uint16_t*)C + idx) = pv;
      } else {
#pragma unroll
        for (int r = 0; r < 4; ++r) {
          const float v = acc[fm][fn][r] + bv;
          if constexpr (MODE == 1)
            ((uint16_t*)C)[(size_t)(row0 + r) * N + col] = f2bf(v);
          else
            ((float*)C)[(size_t)(row0 + r) * N + col] = v;
        }
      }
    }
  }
}

// ----------------------------- flash attention (bf16, HD=64) -----------------------------
// 1-D grid of 512 blocks, 512 threads = 8 waves, each wave owns 32 q rows (Q-tile 256).
// XCD-aware decode: xcd = flat&7 owns bh in [xcd*8, xcd*8+8) -> the 8 q-tile blocks of one
// bh are co-resident on one XCD, K/V L2-local (4 MB working set per XCD).
// K: [b][t][h*64+d]; VT: [b][h][d][t]. Softmax scale pre-folded into Q (exp2 domain).
__global__ __launch_bounds__(512, 4) void attn_kernel(const uint16_t* __restrict__ Q,
                                                      const uint16_t* __restrict__ K,
                                                      const uint16_t* __restrict__ VT,
                                                      uint16_t* __restrict__ AO) {
  constexpr int S = 2048, D = 1024;
  __shared__ uint16_t Kb[2][64 * 64];
  __shared__ uint16_t Vt[64 * 64];     // V^T tile: rows d (64), cols t (64)
  __shared__ uint16_t Ps[8][32 * 64];  // per-wave P tile
  char* KbB = (char*)Kb;
  char* VtB = (char*)Vt;
  char* PsB = (char*)Ps;
  const int tid = threadIdx.x;
  const int w = tid >> 6, l = tid & 63;
  const int lrow = l & 15, g = l >> 4;
  const int flat = blockIdx.x;
  const int bh = (flat & 7) * 8 + (flat >> 6);  // XCD = flat&7 owns 8 consecutive bh
  const int qt = (flat >> 3) & 7;
  const int b = bh >> 4, h = bh & 15;
  const int q0 = qt * 256;
  const int srow = l >> 3;
  const int scb = ((l & 7) ^ srow) << 4;
  const char* Qb = (const char*)Q;
  const char* Kg = (const char*)K;
  const char* Vg = (const char*)VT;

  // hoist Q fragments (A-operand), already scaled by 0.125*log2e
  bf16x8_t qf[2][2];
#pragma unroll
  for (int fm = 0; fm < 2; ++fm)
#pragma unroll
    for (int kk = 0; kk < 2; ++kk)
      qf[fm][kk] = *(const bf16x8_t*)(Qb + (size_t)(b * S + q0 + w * 32 + fm * 16 + lrow) * (D * 2) +
                                      h * 128 + kk * 64 + g * 16);

  float m_run[8], l_run[8];
#pragma unroll
  for (int i = 0; i < 8; ++i) {
    m_run[i] = -1e30f;
    l_run[i] = 0.f;
  }
  f32x4_t acco[2][4] = {};

  // prologue: stage K tile 0 into Kb[0] (wave w covers rows w*8..w*8+7)
  gll16(Kg + (size_t)(b * S + w * 8 + srow) * (D * 2) + h * 128 + scb, KbB + w * 1024);

  int cur = 0;
  for (int t = 0; t < 32; ++t) {
    const int t0 = t * 64;
    // K[cur] landed + all waves done with previous PV (Vt, Kb[cur^1], Ps)
    asm volatile("s_waitcnt vmcnt(0)\ns_barrier" ::: "memory");

    // stage Vt <- tile t (consumed at PV this iter), issued FIRST (oldest in vmcnt FIFO)
    gll16(Vg + (size_t)(bh * 64 + w * 8 + srow) * (S * 2) + t0 * 2 + scb, VtB + w * 1024);
    // prefetch K tile t+1 into the other buffer (stays in flight across barrier B)
    if (t < 31)
      gll16(Kg + (size_t)(b * S + t0 + 64 + w * 8 + srow) * (D * 2) + h * 128 + scb,
            KbB + (cur ^ 1) * 8192 + w * 1024);

    // QK^T from Kb[cur]
    f32x4_t sacc[2][4] = {};
#pragma unroll
    for (int kk = 0; kk < 2; ++kk)
#pragma unroll
      for (int fn = 0; fn < 4; ++fn) {
        const int kr = fn * 16 + lrow;
        bf16x8_t kf = *(const bf16x8_t*)(KbB + cur * 8192 + kr * 128 +
                                         ((kk * 64 + g * 16) ^ ((kr & 7) << 4)));
        sacc[0][fn] = MFMA16(qf[0][kk], kf, sacc[0][fn]);
        sacc[1][fn] = MFMA16(qf[1][kk], kf, sacc[1][fn]);
      }

    // online softmax, exp2 domain (scale already folded into Q)
#pragma unroll
    for (int fm = 0; fm < 2; ++fm)
#pragma unroll
      for (int r = 0; r < 4; ++r) {
        float mx = fmaxf(fmaxf(sacc[fm][0][r], sacc[fm][1][r]),
                         fmaxf(sacc[fm][2][r], sacc[fm][3][r]));
#pragma unroll
        for (int dd = 1; dd < 16; dd <<= 1) mx = fmaxf(mx, __shfl_xor(mx, dd));
        const int slot = fm * 4 + r;
        const float mold = m_run[slot];
        const float mnew = fmaxf(mold, mx);
        const float sc = exp2f(mold - mnew);
        m_run[slot] = mnew;
        float rs = 0.f;
#pragma unroll
        for (int fn = 0; fn < 4; ++fn) {
          const float p = exp2f(sacc[fm][fn][r] - mnew);
          sacc[fm][fn][r] = p;
          rs += p;
        }
#pragma unroll
        for (int dd = 1; dd < 16; dd <<= 1) rs += __shfl_xor(rs, dd);
        l_run[slot] = l_run[slot] * sc + rs;
#pragma unroll
        for (int fd = 0; fd < 4; ++fd) acco[fm][fd][r] *= sc;
      }

    // write P (bf16) to per-wave LDS tile [32 r][64 t], swizzled
#pragma unroll
    for (int fm = 0; fm < 2; ++fm)
#pragma unroll
      for (int fn = 0; fn < 4; ++fn)
#pragma unroll
        for (int r = 0; r < 4; ++r) {
          const int rloc = fm * 16 + g * 4 + r;
          const int tt = fn * 16 + lrow;
          *(uint16_t*)(PsB + w * 4096 + rloc * 128 + ((2 * tt) ^ ((rloc & 7) << 4))) =
              f2bf(sacc[fm][fn][r]);
        }

    // Vt landed (K-next may remain in flight); cross-wave Vt visibility via barrier
    if (t < 31)
      asm volatile("s_waitcnt vmcnt(1)\ns_barrier" ::: "memory");
    else
      asm volatile("s_waitcnt vmcnt(0)\ns_barrier" ::: "memory");

    // PV: O[r, d] += P[r, t] * V^T[d, t]
#pragma unroll
    for (int kk = 0; kk < 2; ++kk) {
      bf16x8_t pf[2];
#pragma unroll
      for (int fm = 0; fm < 2; ++fm) {
        const int pr = fm * 16 + lrow;
        pf[fm] = *(const bf16x8_t*)(PsB + w * 4096 + pr * 128 +
                                    ((kk * 64 + g * 16) ^ ((pr & 7) << 4)));
      }
#pragma unroll
      for (int fd = 0; fd < 4; ++fd) {
        const int vr = fd * 16 + lrow;
        bf16x8_t vf = *(const bf16x8_t*)(VtB + vr * 128 + ((kk * 64 + g * 16) ^ ((vr & 7) << 4)));
        acco[0][fd] = MFMA16(pf[0], vf, acco[0][fd]);
        acco[1][fd] = MFMA16(pf[1], vf, acco[1][fd]);
      }
    }
    cur ^= 1;
  }

  // epilogue: O /= l, write bf16 to AO
#pragma unroll
  for (int fm = 0; fm < 2; ++fm)
#pragma unroll
    for (int r = 0; r < 4; ++r) {
      const float inv = 1.0f / l_run[fm * 4 + r];
      const size_t row = (size_t)(b * S + q0 + w * 32 + fm * 16 + g * 4 + r);
#pragma unroll
      for (int fd = 0; fd < 4; ++fd)
        AO[row * D + h * 64 + fd * 16 + lrow] = f2bf(acco[fm][fd][r] * inv);
    }
}

// ----------------------------- launch -----------------------------
extern "C" void kernel_launch(void* const* d_in, const int* in_sizes, int n_in,
                              void* d_out, int out_size, void* d_ws, size_t ws_size,
                              hipStream_t stream) {
  const float* q_in = (const float*)d_in[0];
  const float* k_in = (const float*)d_in[1];
  const float* v_in = (const float*)d_in[2];
  const float* Wq = (const float*)d_in[3];
  const float* bq = (const float*)d_in[4];
  const float* Wk = (const float*)d_in[5];
  const float* bk = (const float*)d_in[6];
  const float* Wv = (const float*)d_in[7];
  const float* bv = (const float*)d_in[8];
  const float* Wo = (const float*)d_in[9];
  const float* bo = (const float*)d_in[10];

  const size_t MD = (size_t)8192 * 1024;
  const size_t DD = (size_t)1024 * 1024;
  uint16_t* Xq = (uint16_t*)d_ws;
  uint16_t* Xk = Xq + MD;
  uint16_t* Xv = Xk + MD;
  uint16_t* Wqb = Xv + MD;
  uint16_t* Wkb = Wqb + DD;
  uint16_t* Wvb = Wkb + DD;
  uint16_t* Wob = Wvb + DD;
  uint16_t* Qp = Wob + DD;
  uint16_t* Kp = Qp + MD;
  uint16_t* VTp = Kp + MD;
  uint16_t* AO = Xq;  // reuse Xq: consumed by Q projection before attn writes

  const float QSCALE = 0.125f * 1.44269504088896f;  // 1/sqrt(64) * log2(e)

  dim3 cb(256);
  cvt_kernel<<<4096, cb, 0, stream>>>(q_in, Xq, 1048576, 1.0f);
  cvt_kernel<<<4096, cb, 0, stream>>>(k_in, Xk, 1048576, 1.0f);
  cvt_kernel<<<4096, cb, 0, stream>>>(v_in, Xv, 1048576, 1.0f);
  cvt_kernel<<<512, cb, 0, stream>>>(Wq, Wqb, 131072, QSCALE);
  cvt_kernel<<<512, cb, 0, stream>>>(Wk, Wkb, 131072, 1.0f);
  cvt_kernel<<<512, cb, 0, stream>>>(Wv, Wvb, 131072, 1.0f);
  cvt_kernel<<<512, cb, 0, stream>>>(Wo, Wob, 131072, 1.0f);

  dim3 gg(8, 64), gb(256);
  gemm_bt_kernel<1><<<gg, gb, 0, stream>>>(Xq, Wqb, bq, Qp, QSCALE);
  gemm_bt_kernel<1><<<gg, gb, 0, stream>>>(Xk, Wkb, bk, Kp, 1.0f);
  gemm_bt_kernel<2><<<gg, gb, 0, stream>>>(Xv, Wvb, bv, VTp, 1.0f);

  attn_kernel<<<512, 512, 0, stream>>>(Qp, Kp, VTp, AO);

  gemm_bt_kernel<0><<<gg, gb, 0, stream>>>(AO, Wob, bo, d_out, 1.0f);
}

// Round 5
// 520.052 us; speedup vs baseline: 1.2456x; 1.2456x over previous
//
#include <hip/hip_runtime.h>
#include <stdint.h>

typedef __bf16 bf16x8_t __attribute__((ext_vector_type(8)));
typedef float f32x4_t __attribute__((ext_vector_type(4)));
typedef uint16_t u16x8_t __attribute__((ext_vector_type(8)));
typedef uint16_t u16x4_t __attribute__((ext_vector_type(4)));

#define MFMA16(a, b, c) __builtin_amdgcn_mfma_f32_16x16x32_bf16((a), (b), (c), 0, 0, 0)

__device__ __forceinline__ void gll16(const void* g, void* l) {
  typedef const __attribute__((address_space(1))) void* gp1_t;
  typedef __attribute__((address_space(3))) void* lp3_t;
  __builtin_amdgcn_global_load_lds((gp1_t)(uintptr_t)g,
                                   (lp3_t)(uint32_t)(uintptr_t)l, 16, 0, 0);
}

__device__ __forceinline__ uint16_t f2bf(float f) {
  uint32_t u = __float_as_uint(f);
  u += 0x7fffu + ((u >> 16) & 1u);
  return (uint16_t)(u >> 16);
}

// ----------------------------- fp32 -> bf16 convert (optional scale) -----------------------------
__global__ __launch_bounds__(256) void cvt_kernel(const float* __restrict__ in,
                                                  uint16_t* __restrict__ out, int n8,
                                                  float scale) {
  int i = blockIdx.x * 256 + threadIdx.x;
  if (i >= n8) return;
  const float4* p = (const float4*)in;
  float4 a = p[2 * i], b = p[2 * i + 1];
  u16x8_t v;
  v[0] = f2bf(a.x * scale); v[1] = f2bf(a.y * scale);
  v[2] = f2bf(a.z * scale); v[3] = f2bf(a.w * scale);
  v[4] = f2bf(b.x * scale); v[5] = f2bf(b.y * scale);
  v[6] = f2bf(b.z * scale); v[7] = f2bf(b.w * scale);
  ((u16x8_t*)out)[i] = v;
}

// ----------------------------- bf16 NT GEMM: C = A * Bw^T + alpha*bias -----------------------------
// MODE 0: fp32 row-major. MODE 1: bf16 row-major.
// MODE 2: bf16 V^T tiled per head: [bh][vt=t/64][d][tt=t%64]  (8 KB contiguous per KV tile)
// MODE 3: bf16 K packed per head: [bh][t][d]                  (8 KB contiguous per KV tile)
template <int MODE>
__global__ __launch_bounds__(256) void gemm_bt_kernel(const uint16_t* __restrict__ A,
                                                      const uint16_t* __restrict__ Bw,
                                                      const float* __restrict__ bias,
                                                      void* __restrict__ C, float alpha) {
  constexpr int K = 1024, N = 1024;
  __shared__ uint16_t As[128 * 64];
  __shared__ uint16_t Bs[128 * 64];
  char* AsB = (char*)As;
  char* BsB = (char*)Bs;
  const int tid = threadIdx.x;
  const int w = tid >> 6, l = tid & 63;
  const int wr = w >> 1, wc = w & 1;
  const int lrow = l & 15, g = l >> 4;
  const int bm0 = blockIdx.y * 128, bn0 = blockIdx.x * 128;
  const int srow = l >> 3;
  const int scb = ((l & 7) ^ srow) << 4;
  const char* Ab = (const char*)A;
  const char* Bb = (const char*)Bw;
  f32x4_t acc[4][4] = {};

  for (int it = 0; it < K / 64; ++it) {
    const int k0 = it * 64;
    __syncthreads();
#pragma unroll
    for (int s = 0; s < 4; ++s) {
      const int rbase = s * 32 + w * 8;
      gll16(Ab + (size_t)(bm0 + rbase + srow) * (K * 2) + k0 * 2 + scb, AsB + rbase * 128);
      gll16(Bb + (size_t)(bn0 + rbase + srow) * (K * 2) + k0 * 2 + scb, BsB + rbase * 128);
    }
    asm volatile("s_waitcnt vmcnt(0)" ::: "memory");
    __syncthreads();
#pragma unroll
    for (int kk = 0; kk < 2; ++kk) {
      bf16x8_t af[4], bfr[4];
#pragma unroll
      for (int f = 0; f < 4; ++f) {
        const int ar = wr * 64 + f * 16 + lrow;
        af[f] = *(const bf16x8_t*)(AsB + ar * 128 + ((kk * 64 + g * 16) ^ ((ar & 7) << 4)));
        const int br = wc * 64 + f * 16 + lrow;
        bfr[f] = *(const bf16x8_t*)(BsB + br * 128 + ((kk * 64 + g * 16) ^ ((br & 7) << 4)));
      }
#pragma unroll
      for (int fm = 0; fm < 4; ++fm)
#pragma unroll
        for (int fn = 0; fn < 4; ++fn)
          acc[fm][fn] = MFMA16(af[fm], bfr[fn], acc[fm][fn]);
    }
  }
  // epilogue: C/D layout col = lane&15, row = (lane>>4)*4 + reg
#pragma unroll
  for (int fn = 0; fn < 4; ++fn) {
    const int col = bn0 + wc * 64 + fn * 16 + lrow;
    const float bv = bias[col] * alpha;
#pragma unroll
    for (int fm = 0; fm < 4; ++fm) {
      const int row0 = bm0 + wr * 64 + fm * 16 + g * 4;
      if constexpr (MODE == 2) {
        const int b = row0 >> 11, t = row0 & 2047;
        const int bhh = (b << 4) + (col >> 6), d = col & 63;
        u16x4_t pv;
#pragma unroll
        for (int r = 0; r < 4; ++r) pv[r] = f2bf(acc[fm][fn][r] + bv);
        const size_t idx = (((size_t)bhh * 32 + (t >> 6)) * 64 + d) * 64 + (t & 63);
        *(u16x4_t*)((uint16_t*)C + idx) = pv;
      } else if constexpr (MODE == 3) {
        const int b = row0 >> 11, t = row0 & 2047;
        const int bhh = (b << 4) + (col >> 6), d = col & 63;
#pragma unroll
        for (int r = 0; r < 4; ++r)
          ((uint16_t*)C)[((size_t)bhh * 2048 + t + r) * 64 + d] = f2bf(acc[fm][fn][r] + bv);
      } else {
#pragma unroll
        for (int r = 0; r < 4; ++r) {
          const float v = acc[fm][fn][r] + bv;
          if constexpr (MODE == 1)
            ((uint16_t*)C)[(size_t)(row0 + r) * N + col] = f2bf(v);
          else
            ((float*)C)[(size_t)(row0 + r) * N + col] = v;
        }
      }
    }
  }
}

// ----------------------------- flash attention (bf16, HD=64) -----------------------------
// 512 blocks x 512 threads (8 waves, 32 q-rows each -> Q-tile 256). KV tile 64.
// XCD-aware decode: xcd = flat&7 owns bh in [xcd*8, xcd*8+8).
// Kh: [bh][t][64] packed per head; VT: [bh][vt][d][tt] tiled per head -> every staged tile is
// one contiguous 8 KB block (1 KB linear per wave gll16). K+V symmetric double buffer,
// ONE barrier + ONE vmcnt(0) per iteration. Softmax scale pre-folded into Q (exp2 domain).
__global__ __launch_bounds__(512, 4) void attn_kernel(const uint16_t* __restrict__ Q,
                                                      const uint16_t* __restrict__ Kh,
                                                      const uint16_t* __restrict__ VT,
                                                      uint16_t* __restrict__ AO) {
  constexpr int S = 2048, D = 1024;
  __shared__ uint16_t Kb[2][64 * 64];
  __shared__ uint16_t Vb[2][64 * 64];
  __shared__ uint16_t Ps[8][32 * 64];  // per-wave P tile (wave-private)
  char* KbB = (char*)Kb;
  char* VbB = (char*)Vb;
  char* PsB = (char*)Ps;
  const int tid = threadIdx.x;
  const int w = tid >> 6, l = tid & 63;
  const int lrow = l & 15, g = l >> 4;
  const int flat = blockIdx.x;
  const int bh = (flat & 7) * 8 + (flat >> 6);  // XCD = flat&7 owns 8 consecutive bh
  const int qt = (flat >> 3) & 7;
  const int b = bh >> 4, h = bh & 15;
  const int q0 = qt * 256;
  const int srow = l >> 3;
  // within-tile source byte for this lane (contiguous 1 KB per wave, XOR-perm inside 128 B rows)
  const int sofs = (w * 8 + srow) * 128 + (((l & 7) ^ srow) << 4);
  const char* Kg = (const char*)Kh + (size_t)bh * 262144;  // 2048*64*2 B per head
  const char* Vg = (const char*)VT + (size_t)bh * 262144;
  const char* Qb = (const char*)Q;

  // hoist Q fragments (A-operand), already scaled by 0.125*log2e
  bf16x8_t qf[2][2];
#pragma unroll
  for (int fm = 0; fm < 2; ++fm)
#pragma unroll
    for (int kk = 0; kk < 2; ++kk)
      qf[fm][kk] = *(const bf16x8_t*)(Qb + (size_t)(b * S + q0 + w * 32 + fm * 16 + lrow) * (D * 2) +
                                      h * 128 + kk * 64 + g * 16);

  float m_run[8], l_run[8];
#pragma unroll
  for (int i = 0; i < 8; ++i) {
    m_run[i] = -1e30f;
    l_run[i] = 0.f;
  }
  f32x4_t acco[2][4] = {};

  // prologue: stage tile 0 (K and V) into buffer 0
  gll16(Kg + sofs, KbB + w * 1024);
  gll16(Vg + sofs, VbB + w * 1024);

  for (int t = 0; t < 32; ++t) {
    const int cur = (t & 1) * 8192;
    // tile t landed (this wave's parts) + all waves past previous iteration's reads
    asm volatile("s_waitcnt vmcnt(0)\ns_barrier" ::: "memory");

    // prefetch tile t+1 into the other buffer; full compute phase to land
    if (t < 31) {
      const size_t nb = (size_t)(t + 1) * 8192 + sofs;
      gll16(Kg + nb, KbB + (cur ^ 8192) + w * 1024);
      gll16(Vg + nb, VbB + (cur ^ 8192) + w * 1024);
    }

    // QK^T from Kb[cur]
    f32x4_t sacc[2][4] = {};
#pragma unroll
    for (int kk = 0; kk < 2; ++kk)
#pragma unroll
      for (int fn = 0; fn < 4; ++fn) {
        const int kr = fn * 16 + lrow;
        bf16x8_t kf = *(const bf16x8_t*)(KbB + cur + kr * 128 +
                                         ((kk * 64 + g * 16) ^ ((kr & 7) << 4)));
        sacc[0][fn] = MFMA16(qf[0][kk], kf, sacc[0][fn]);
        sacc[1][fn] = MFMA16(qf[1][kk], kf, sacc[1][fn]);
      }

    // online softmax, exp2 domain (scale already folded into Q)
#pragma unroll
    for (int fm = 0; fm < 2; ++fm)
#pragma unroll
      for (int r = 0; r < 4; ++r) {
        float mx = fmaxf(fmaxf(sacc[fm][0][r], sacc[fm][1][r]),
                         fmaxf(sacc[fm][2][r], sacc[fm][3][r]));
#pragma unroll
        for (int dd = 1; dd < 16; dd <<= 1) mx = fmaxf(mx, __shfl_xor(mx, dd));
        const int slot = fm * 4 + r;
        const float mold = m_run[slot];
        const float mnew = fmaxf(mold, mx);
        const float sc = exp2f(mold - mnew);
        m_run[slot] = mnew;
        float rs = 0.f;
#pragma unroll
        for (int fn = 0; fn < 4; ++fn) {
          const float p = exp2f(sacc[fm][fn][r] - mnew);
          sacc[fm][fn][r] = p;
          rs += p;
        }
#pragma unroll
        for (int dd = 1; dd < 16; dd <<= 1) rs += __shfl_xor(rs, dd);
        l_run[slot] = l_run[slot] * sc + rs;
#pragma unroll
        for (int fd = 0; fd < 4; ++fd) acco[fm][fd][r] *= sc;
      }

    // write P (bf16) to wave-private LDS tile [32 r][64 t], swizzled (no barrier needed)
#pragma unroll
    for (int fm = 0; fm < 2; ++fm)
#pragma unroll
      for (int fn = 0; fn < 4; ++fn)
#pragma unroll
        for (int r = 0; r < 4; ++r) {
          const int rloc = fm * 16 + g * 4 + r;
          const int tt = fn * 16 + lrow;
          *(uint16_t*)(PsB + w * 4096 + rloc * 128 + ((2 * tt) ^ ((rloc & 7) << 4))) =
              f2bf(sacc[fm][fn][r]);
        }

    // PV: O[r, d] += P[r, t] * V^T[d, t]   (Vb[cur] synced at this iteration's top barrier)
#pragma unroll
    for (int kk = 0; kk < 2; ++kk) {
      bf16x8_t pf[2];
#pragma unroll
      for (int fm = 0; fm < 2; ++fm) {
        const int pr = fm * 16 + lrow;
        pf[fm] = *(const bf16x8_t*)(PsB + w * 4096 + pr * 128 +
                                    ((kk * 64 + g * 16) ^ ((pr & 7) << 4)));
      }
#pragma unroll
      for (int fd = 0; fd < 4; ++fd) {
        const int vr = fd * 16 + lrow;
        bf16x8_t vf = *(const bf16x8_t*)(VbB + cur + vr * 128 +
                                         ((kk * 64 + g * 16) ^ ((vr & 7) << 4)));
        acco[0][fd] = MFMA16(pf[0], vf, acco[0][fd]);
        acco[1][fd] = MFMA16(pf[1], vf, acco[1][fd]);
      }
    }
  }

  // epilogue: O /= l, write bf16 to AO (row-major [b][s][D] for the output GEMM)
#pragma unroll
  for (int fm = 0; fm < 2; ++fm)
#pragma unroll
    for (int r = 0; r < 4; ++r) {
      const float inv = 1.0f / l_run[fm * 4 + r];
      const size_t row = (size_t)(b * S + q0 + w * 32 + fm * 16 + g * 4 + r);
#pragma unroll
      for (int fd = 0; fd < 4; ++fd)
        AO[row * D + h * 64 + fd * 16 + lrow] = f2bf(acco[fm][fd][r] * inv);
    }
}

// ----------------------------- launch -----------------------------
extern "C" void kernel_launch(void* const* d_in, const int* in_sizes, int n_in,
                              void* d_out, int out_size, void* d_ws, size_t ws_size,
                              hipStream_t stream) {
  const float* q_in = (const float*)d_in[0];
  const float* k_in = (const float*)d_in[1];
  const float* v_in = (const float*)d_in[2];
  const float* Wq = (const float*)d_in[3];
  const float* bq = (const float*)d_in[4];
  const float* Wk = (const float*)d_in[5];
  const float* bk = (const float*)d_in[6];
  const float* Wv = (const float*)d_in[7];
  const float* bv = (const float*)d_in[8];
  const float* Wo = (const float*)d_in[9];
  const float* bo = (const float*)d_in[10];

  const size_t MD = (size_t)8192 * 1024;
  const size_t DD = (size_t)1024 * 1024;
  uint16_t* Xq = (uint16_t*)d_ws;
  uint16_t* Xk = Xq + MD;
  uint16_t* Xv = Xk + MD;
  uint16_t* Wqb = Xv + MD;
  uint16_t* Wkb = Wqb + DD;
  uint16_t* Wvb = Wkb + DD;
  uint16_t* Wob = Wvb + DD;
  uint16_t* Qp = Wob + DD;
  uint16_t* Kp = Qp + MD;
  uint16_t* VTp = Kp + MD;
  uint16_t* AO = Xq;  // reuse Xq: consumed by Q projection before attn writes

  const float QSCALE = 0.125f * 1.44269504088896f;  // 1/sqrt(64) * log2(e)

  dim3 cb(256);
  cvt_kernel<<<4096, cb, 0, stream>>>(q_in, Xq, 1048576, 1.0f);
  cvt_kernel<<<4096, cb, 0, stream>>>(k_in, Xk, 1048576, 1.0f);
  cvt_kernel<<<4096, cb, 0, stream>>>(v_in, Xv, 1048576, 1.0f);
  cvt_kernel<<<512, cb, 0, stream>>>(Wq, Wqb, 131072, QSCALE);
  cvt_kernel<<<512, cb, 0, stream>>>(Wk, Wkb, 131072, 1.0f);
  cvt_kernel<<<512, cb, 0, stream>>>(Wv, Wvb, 131072, 1.0f);
  cvt_kernel<<<512, cb, 0, stream>>>(Wo, Wob, 131072, 1.0f);

  dim3 gg(8, 64), gb(256);
  gemm_bt_kernel<1><<<gg, gb, 0, stream>>>(Xq, Wqb, bq, Qp, QSCALE);
  gemm_bt_kernel<3><<<gg, gb, 0, stream>>>(Xk, Wkb, bk, Kp, 1.0f);
  gemm_bt_kernel<2><<<gg, gb, 0, stream>>>(Xv, Wvb, bv, VTp, 1.0f);

  attn_kernel<<<512, 512, 0, stream>>>(Qp, Kp, VTp, AO);

  gemm_bt_kernel<0><<<gg, gb, 0, stream>>>(AO, Wob, bo, d_out, 1.0f);
}

// Round 6
// 518.617 us; speedup vs baseline: 1.2490x; 1.0028x over previous
//
#include <hip/hip_runtime.h>
#include <stdint.h>

typedef __bf16 bf16x8_t __attribute__((ext_vector_type(8)));
typedef float f32x4_t __attribute__((ext_vector_type(4)));
typedef uint16_t u16x8_t __attribute__((ext_vector_type(8)));
typedef uint16_t u16x4_t __attribute__((ext_vector_type(4)));

#define MFMA16(a, b, c) __builtin_amdgcn_mfma_f32_16x16x32_bf16((a), (b), (c), 0, 0, 0)

__device__ __forceinline__ void gll16(const void* g, void* l) {
  typedef const __attribute__((address_space(1))) void* gp1_t;
  typedef __attribute__((address_space(3))) void* lp3_t;
  __builtin_amdgcn_global_load_lds((gp1_t)(uintptr_t)g,
                                   (lp3_t)(uint32_t)(uintptr_t)l, 16, 0, 0);
}

__device__ __forceinline__ uint16_t f2bf(float f) {
  uint32_t u = __float_as_uint(f);
  u += 0x7fffu + ((u >> 16) & 1u);
  return (uint16_t)(u >> 16);
}

// ----------------------------- fp32 -> bf16 convert (optional scale) -----------------------------
__global__ __launch_bounds__(256) void cvt_kernel(const float* __restrict__ in,
                                                  uint16_t* __restrict__ out, int n8,
                                                  float scale) {
  int i = blockIdx.x * 256 + threadIdx.x;
  if (i >= n8) return;
  const float4* p = (const float4*)in;
  float4 a = p[2 * i], b = p[2 * i + 1];
  u16x8_t v;
  v[0] = f2bf(a.x * scale); v[1] = f2bf(a.y * scale);
  v[2] = f2bf(a.z * scale); v[3] = f2bf(a.w * scale);
  v[4] = f2bf(b.x * scale); v[5] = f2bf(b.y * scale);
  v[6] = f2bf(b.z * scale); v[7] = f2bf(b.w * scale);
  ((u16x8_t*)out)[i] = v;
}

// ----------------------------- bf16 NT GEMM: C = A * Bw^T + alpha*bias -----------------------------
// MODE 0: fp32 row-major. MODE 1: bf16 row-major.
// MODE 2: bf16 V^T tiled per head: [bh][vt=t/64][d][tt=t%64]  (8 KB contiguous per KV tile)
// MODE 3: bf16 K packed per head: [bh][t][d]                  (8 KB contiguous per KV tile)
template <int MODE>
__global__ __launch_bounds__(256) void gemm_bt_kernel(const uint16_t* __restrict__ A,
                                                      const uint16_t* __restrict__ Bw,
                                                      const float* __restrict__ bias,
                                                      void* __restrict__ C, float alpha) {
  constexpr int K = 1024, N = 1024;
  __shared__ uint16_t As[128 * 64];
  __shared__ uint16_t Bs[128 * 64];
  char* AsB = (char*)As;
  char* BsB = (char*)Bs;
  const int tid = threadIdx.x;
  const int w = tid >> 6, l = tid & 63;
  const int wr = w >> 1, wc = w & 1;
  const int lrow = l & 15, g = l >> 4;
  const int bm0 = blockIdx.y * 128, bn0 = blockIdx.x * 128;
  const int srow = l >> 3;
  const int scb = ((l & 7) ^ srow) << 4;
  const char* Ab = (const char*)A;
  const char* Bb = (const char*)Bw;
  f32x4_t acc[4][4] = {};

  for (int it = 0; it < K / 64; ++it) {
    const int k0 = it * 64;
    __syncthreads();
#pragma unroll
    for (int s = 0; s < 4; ++s) {
      const int rbase = s * 32 + w * 8;
      gll16(Ab + (size_t)(bm0 + rbase + srow) * (K * 2) + k0 * 2 + scb, AsB + rbase * 128);
      gll16(Bb + (size_t)(bn0 + rbase + srow) * (K * 2) + k0 * 2 + scb, BsB + rbase * 128);
    }
    asm volatile("s_waitcnt vmcnt(0)" ::: "memory");
    __syncthreads();
#pragma unroll
    for (int kk = 0; kk < 2; ++kk) {
      bf16x8_t af[4], bfr[4];
#pragma unroll
      for (int f = 0; f < 4; ++f) {
        const int ar = wr * 64 + f * 16 + lrow;
        af[f] = *(const bf16x8_t*)(AsB + ar * 128 + ((kk * 64 + g * 16) ^ ((ar & 7) << 4)));
        const int br = wc * 64 + f * 16 + lrow;
        bfr[f] = *(const bf16x8_t*)(BsB + br * 128 + ((kk * 64 + g * 16) ^ ((br & 7) << 4)));
      }
#pragma unroll
      for (int fm = 0; fm < 4; ++fm)
#pragma unroll
        for (int fn = 0; fn < 4; ++fn)
          acc[fm][fn] = MFMA16(af[fm], bfr[fn], acc[fm][fn]);
    }
  }
  // epilogue: C/D layout col = lane&15, row = (lane>>4)*4 + reg
#pragma unroll
  for (int fn = 0; fn < 4; ++fn) {
    const int col = bn0 + wc * 64 + fn * 16 + lrow;
    const float bv = bias[col] * alpha;
#pragma unroll
    for (int fm = 0; fm < 4; ++fm) {
      const int row0 = bm0 + wr * 64 + fm * 16 + g * 4;
      if constexpr (MODE == 2) {
        const int b = row0 >> 11, t = row0 & 2047;
        const int bhh = (b << 4) + (col >> 6), d = col & 63;
        u16x4_t pv;
#pragma unroll
        for (int r = 0; r < 4; ++r) pv[r] = f2bf(acc[fm][fn][r] + bv);
        const size_t idx = (((size_t)bhh * 32 + (t >> 6)) * 64 + d) * 64 + (t & 63);
        *(u16x4_t*)((uint16_t*)C + idx) = pv;
      } else if constexpr (MODE == 3) {
        const int b = row0 >> 11, t = row0 & 2047;
        const int bhh = (b << 4) + (col >> 6), d = col & 63;
#pragma unroll
        for (int r = 0; r < 4; ++r)
          ((uint16_t*)C)[((size_t)bhh * 2048 + t + r) * 64 + d] = f2bf(acc[fm][fn][r] + bv);
      } else {
#pragma unroll
        for (int r = 0; r < 4; ++r) {
          const float v = acc[fm][fn][r] + bv;
          if constexpr (MODE == 1)
            ((uint16_t*)C)[(size_t)(row0 + r) * N + col] = f2bf(v);
          else
            ((float*)C)[(size_t)(row0 + r) * N + col] = v;
        }
      }
    }
  }
}

// ----------------------------- flash attention (bf16, HD=64) -----------------------------
// 512 blocks x 512 threads (8 waves, 32 q-rows each -> Q-tile 256). KV tile 64.
// XCD-aware decode: xcd = flat&7 owns bh in [xcd*8, xcd*8+8).
// Kh: [bh][t][64] packed per head; VT: [bh][vt][d][tt] tiled per head -> every staged tile is
// one contiguous 8 KB block (1 KB linear per wave gll16). K+V symmetric double buffer,
// ONE barrier + ONE vmcnt(0) per iteration. Softmax scale pre-folded into Q (exp2 domain).
__global__ __launch_bounds__(512, 4) void attn_kernel(const uint16_t* __restrict__ Q,
                                                      const uint16_t* __restrict__ Kh,
                                                      const uint16_t* __restrict__ VT,
                                                      uint16_t* __restrict__ AO) {
  constexpr int S = 2048, D = 1024;
  __shared__ uint16_t Kb[2][64 * 64];
  __shared__ uint16_t Vb[2][64 * 64];
  __shared__ uint16_t Ps[8][32 * 64];  // per-wave P tile (wave-private)
  char* KbB = (char*)Kb;
  char* VbB = (char*)Vb;
  char* PsB = (char*)Ps;
  const int tid = threadIdx.x;
  const int w = tid >> 6, l = tid & 63;
  const int lrow = l & 15, g = l >> 4;
  const int flat = blockIdx.x;
  const int bh = (flat & 7) * 8 + (flat >> 6);  // XCD = flat&7 owns 8 consecutive bh
  const int qt = (flat >> 3) & 7;
  const int b = bh >> 4, h = bh & 15;
  const int q0 = qt * 256;
  const int srow = l >> 3;
  // within-tile source byte for this lane (contiguous 1 KB per wave, XOR-perm inside 128 B rows)
  const int sofs = (w * 8 + srow) * 128 + (((l & 7) ^ srow) << 4);
  const char* Kg = (const char*)Kh + (size_t)bh * 262144;  // 2048*64*2 B per head
  const char* Vg = (const char*)VT + (size_t)bh * 262144;
  const char* Qb = (const char*)Q;

  // hoist Q fragments (A-operand), already scaled by 0.125*log2e
  bf16x8_t qf[2][2];
#pragma unroll
  for (int fm = 0; fm < 2; ++fm)
#pragma unroll
    for (int kk = 0; kk < 2; ++kk)
      qf[fm][kk] = *(const bf16x8_t*)(Qb + (size_t)(b * S + q0 + w * 32 + fm * 16 + lrow) * (D * 2) +
                                      h * 128 + kk * 64 + g * 16);

  float m_run[8], l_run[8];
#pragma unroll
  for (int i = 0; i < 8; ++i) {
    m_run[i] = -1e30f;
    l_run[i] = 0.f;
  }
  f32x4_t acco[2][4] = {};

  // prologue: stage tile 0 (K and V) into buffer 0
  gll16(Kg + sofs, KbB + w * 1024);
  gll16(Vg + sofs, VbB + w * 1024);

  for (int t = 0; t < 32; ++t) {
    const int cur = (t & 1) * 8192;
    // tile t landed (this wave's parts) + all waves past previous iteration's reads
    asm volatile("s_waitcnt vmcnt(0)\ns_barrier" ::: "memory");

    // prefetch tile t+1 into the other buffer; full compute phase to land
    if (t < 31) {
      const size_t nb = (size_t)(t + 1) * 8192 + sofs;
      gll16(Kg + nb, KbB + (cur ^ 8192) + w * 1024);
      gll16(Vg + nb, VbB + (cur ^ 8192) + w * 1024);
    }

    // QK^T from Kb[cur]
    f32x4_t sacc[2][4] = {};
#pragma unroll
    for (int kk = 0; kk < 2; ++kk)
#pragma unroll
      for (int fn = 0; fn < 4; ++fn) {
        const int kr = fn * 16 + lrow;
        bf16x8_t kf = *(const bf16x8_t*)(KbB + cur + kr * 128 +
                                         ((kk * 64 + g * 16) ^ ((kr & 7) << 4)));
        sacc[0][fn] = MFMA16(qf[0][kk], kf, sacc[0][fn]);
        sacc[1][fn] = MFMA16(qf[1][kk], kf, sacc[1][fn]);
      }

    // online softmax, exp2 domain (scale already folded into Q)
#pragma unroll
    for (int fm = 0; fm < 2; ++fm)
#pragma unroll
      for (int r = 0; r < 4; ++r) {
        float mx = fmaxf(fmaxf(sacc[fm][0][r], sacc[fm][1][r]),
                         fmaxf(sacc[fm][2][r], sacc[fm][3][r]));
#pragma unroll
        for (int dd = 1; dd < 16; dd <<= 1) mx = fmaxf(mx, __shfl_xor(mx, dd));
        const int slot = fm * 4 + r;
        const float mold = m_run[slot];
        const float mnew = fmaxf(mold, mx);
        const float sc = exp2f(mold - mnew);
        m_run[slot] = mnew;
        float rs = 0.f;
#pragma unroll
        for (int fn = 0; fn < 4; ++fn) {
          const float p = exp2f(sacc[fm][fn][r] - mnew);
          sacc[fm][fn][r] = p;
          rs += p;
        }
#pragma unroll
        for (int dd = 1; dd < 16; dd <<= 1) rs += __shfl_xor(rs, dd);
        l_run[slot] = l_run[slot] * sc + rs;
#pragma unroll
        for (int fd = 0; fd < 4; ++fd) acco[fm][fd][r] *= sc;
      }

    // write P (bf16) to wave-private LDS tile [32 r][64 t], swizzled (no barrier needed)
#pragma unroll
    for (int fm = 0; fm < 2; ++fm)
#pragma unroll
      for (int fn = 0; fn < 4; ++fn)
#pragma unroll
        for (int r = 0; r < 4; ++r) {
          const int rloc = fm * 16 + g * 4 + r;
          const int tt = fn * 16 + lrow;
          *(uint16_t*)(PsB + w * 4096 + rloc * 128 + ((2 * tt) ^ ((rloc & 7) << 4))) =
              f2bf(sacc[fm][fn][r]);
        }

    // PV: O[r, d] += P[r, t] * V^T[d, t]   (Vb[cur] synced at this iteration's top barrier)
#pragma unroll
    for (int kk = 0; kk < 2; ++kk) {
      bf16x8_t pf[2];
#pragma unroll
      for (int fm = 0; fm < 2; ++fm) {
        const int pr = fm * 16 + lrow;
        pf[fm] = *(const bf16x8_t*)(PsB + w * 4096 + pr * 128 +
                                    ((kk * 64 + g * 16) ^ ((pr & 7) << 4)));
      }
#pragma unroll
      for (int fd = 0; fd < 4; ++fd) {
        const int vr = fd * 16 + lrow;
        bf16x8_t vf = *(const bf16x8_t*)(VbB + cur + vr * 128 +
                                         ((kk * 64 + g * 16) ^ ((vr & 7) << 4)));
        acco[0][fd] = MFMA16(pf[0], vf, acco[0][fd]);
        acco[1][fd] = MFMA16(pf[1], vf, acco[1][fd]);
      }
    }
  }

  // epilogue: O /= l, write bf16 to AO (row-major [b][s][D] for the output GEMM)
#pragma unroll
  for (int fm = 0; fm < 2; ++fm)
#pragma unroll
    for (int r = 0; r < 4; ++r) {
      const float inv = 1.0f / l_run[fm * 4 + r];
      const size_t row = (size_t)(b * S + q0 + w * 32 + fm * 16 + g * 4 + r);
#pragma unroll
      for (int fd = 0; fd < 4; ++fd)
        AO[row * D + h * 64 + fd * 16 + lrow] = f2bf(acco[fm][fd][r] * inv);
    }
}

// ----------------------------- launch -----------------------------
extern "C" void kernel_launch(void* const* d_in, const int* in_sizes, int n_in,
                              void* d_out, int out_size, void* d_ws, size_t ws_size,
                              hipStream_t stream) {
  const float* q_in = (const float*)d_in[0];
  const float* k_in = (const float*)d_in[1];
  const float* v_in = (const float*)d_in[2];
  const float* Wq = (const float*)d_in[3];
  const float* bq = (const float*)d_in[4];
  const float* Wk = (const float*)d_in[5];
  const float* bk = (const float*)d_in[6];
  const float* Wv = (const float*)d_in[7];
  const float* bv = (const float*)d_in[8];
  const float* Wo = (const float*)d_in[9];
  const float* bo = (const float*)d_in[10];

  const size_t MD = (size_t)8192 * 1024;
  const size_t DD = (size_t)1024 * 1024;
  uint16_t* Xq = (uint16_t*)d_ws;
  uint16_t* Xk = Xq + MD;
  uint16_t* Xv = Xk + MD;
  uint16_t* Wqb = Xv + MD;
  uint16_t* Wkb = Wqb + DD;
  uint16_t* Wvb = Wkb + DD;
  uint16_t* Wob = Wvb + DD;
  uint16_t* Qp = Wob + DD;
  uint16_t* Kp = Qp + MD;
  uint16_t* VTp = Kp + MD;
  uint16_t* AO = Xq;  // reuse Xq: consumed by Q projection before attn writes

  const float QSCALE = 0.125f * 1.44269504088896f;  // 1/sqrt(64) * log2(e)

  dim3 cb(256);
  cvt_kernel<<<4096, cb, 0, stream>>>(q_in, Xq, 1048576, 1.0f);
  cvt_kernel<<<4096, cb, 0, stream>>>(k_in, Xk, 1048576, 1.0f);
  cvt_kernel<<<4096, cb, 0, stream>>>(v_in, Xv, 1048576, 1.0f);
  cvt_kernel<<<512, cb, 0, stream>>>(Wq, Wqb, 131072, QSCALE);
  cvt_kernel<<<512, cb, 0, stream>>>(Wk, Wkb, 131072, 1.0f);
  cvt_kernel<<<512, cb, 0, stream>>>(Wv, Wvb, 131072, 1.0f);
  cvt_kernel<<<512, cb, 0, stream>>>(Wo, Wob, 131072, 1.0f);

  dim3 gg(8, 64), gb(256);
  gemm_bt_kernel<1><<<gg, gb, 0, stream>>>(Xq, Wqb, bq, Qp, QSCALE);
  gemm_bt_kernel<3><<<gg, gb, 0, stream>>>(Xk, Wkb, bk, Kp, 1.0f);
  gemm_bt_kernel<2><<<gg, gb, 0, stream>>>(Xv, Wvb, bv, VTp, 1.0f);

  attn_kernel<<<512, 512, 0, stream>>>(Qp, Kp, VTp, AO);

  gemm_bt_kernel<0><<<gg, gb, 0, stream>>>(AO, Wob, bo, d_out, 1.0f);
}

// Round 7
// 517.574 us; speedup vs baseline: 1.2516x; 1.0020x over previous
//
#include <hip/hip_runtime.h>
#include <stdint.h>

typedef __bf16 bf16x8_t __attribute__((ext_vector_type(8)));
typedef float f32x4_t __attribute__((ext_vector_type(4)));
typedef uint16_t u16x8_t __attribute__((ext_vector_type(8)));
typedef uint16_t u16x4_t __attribute__((ext_vector_type(4)));

#define MFMA16(a, b, c) __builtin_amdgcn_mfma_f32_16x16x32_bf16((a), (b), (c), 0, 0, 0)

__device__ __forceinline__ void gll16(const void* g, void* l) {
  typedef const __attribute__((address_space(1))) void* gp1_t;
  typedef __attribute__((address_space(3))) void* lp3_t;
  __builtin_amdgcn_global_load_lds((gp1_t)(uintptr_t)g,
                                   (lp3_t)(uint32_t)(uintptr_t)l, 16, 0, 0);
}

__device__ __forceinline__ uint16_t f2bf(float f) {
  uint32_t u = __float_as_uint(f);
  u += 0x7fffu + ((u >> 16) & 1u);
  return (uint16_t)(u >> 16);
}

// ----------------------------- fp32 -> bf16 convert (optional scale) -----------------------------
__global__ __launch_bounds__(256) void cvt_kernel(const float* __restrict__ in,
                                                  uint16_t* __restrict__ out, int n8,
                                                  float scale) {
  int i = blockIdx.x * 256 + threadIdx.x;
  if (i >= n8) return;
  const float4* p = (const float4*)in;
  float4 a = p[2 * i], b = p[2 * i + 1];
  u16x8_t v;
  v[0] = f2bf(a.x * scale); v[1] = f2bf(a.y * scale);
  v[2] = f2bf(a.z * scale); v[3] = f2bf(a.w * scale);
  v[4] = f2bf(b.x * scale); v[5] = f2bf(b.y * scale);
  v[6] = f2bf(b.z * scale); v[7] = f2bf(b.w * scale);
  ((u16x8_t*)out)[i] = v;
}

// ----------------------------- bf16 NT GEMM: C = A * Bw^T + alpha*bias -----------------------------
// MODE 0: fp32 row-major. MODE 1: bf16 row-major.
// MODE 2: bf16 V^T tiled per head: [bh][vt=t/64][d][tt=t%64]  (8 KB contiguous per KV tile)
// MODE 3: bf16 K packed per head: [bh][t][d]                  (8 KB contiguous per KV tile)
template <int MODE>
__global__ __launch_bounds__(256) void gemm_bt_kernel(const uint16_t* __restrict__ A,
                                                      const uint16_t* __restrict__ Bw,
                                                      const float* __restrict__ bias,
                                                      void* __restrict__ C, float alpha) {
  constexpr int K = 1024, N = 1024;
  __shared__ uint16_t As[128 * 64];
  __shared__ uint16_t Bs[128 * 64];
  char* AsB = (char*)As;
  char* BsB = (char*)Bs;
  const int tid = threadIdx.x;
  const int w = tid >> 6, l = tid & 63;
  const int wr = w >> 1, wc = w & 1;
  const int lrow = l & 15, g = l >> 4;
  const int bm0 = blockIdx.y * 128, bn0 = blockIdx.x * 128;
  const int srow = l >> 3;
  const int scb = ((l & 7) ^ srow) << 4;
  const char* Ab = (const char*)A;
  const char* Bb = (const char*)Bw;
  f32x4_t acc[4][4] = {};

  for (int it = 0; it < K / 64; ++it) {
    const int k0 = it * 64;
    __syncthreads();
#pragma unroll
    for (int s = 0; s < 4; ++s) {
      const int rbase = s * 32 + w * 8;
      gll16(Ab + (size_t)(bm0 + rbase + srow) * (K * 2) + k0 * 2 + scb, AsB + rbase * 128);
      gll16(Bb + (size_t)(bn0 + rbase + srow) * (K * 2) + k0 * 2 + scb, BsB + rbase * 128);
    }
    asm volatile("s_waitcnt vmcnt(0)" ::: "memory");
    __syncthreads();
#pragma unroll
    for (int kk = 0; kk < 2; ++kk) {
      bf16x8_t af[4], bfr[4];
#pragma unroll
      for (int f = 0; f < 4; ++f) {
        const int ar = wr * 64 + f * 16 + lrow;
        af[f] = *(const bf16x8_t*)(AsB + ar * 128 + ((kk * 64 + g * 16) ^ ((ar & 7) << 4)));
        const int br = wc * 64 + f * 16 + lrow;
        bfr[f] = *(const bf16x8_t*)(BsB + br * 128 + ((kk * 64 + g * 16) ^ ((br & 7) << 4)));
      }
#pragma unroll
      for (int fm = 0; fm < 4; ++fm)
#pragma unroll
        for (int fn = 0; fn < 4; ++fn)
          acc[fm][fn] = MFMA16(af[fm], bfr[fn], acc[fm][fn]);
    }
  }
  // epilogue: C/D layout col = lane&15, row = (lane>>4)*4 + reg
#pragma unroll
  for (int fn = 0; fn < 4; ++fn) {
    const int col = bn0 + wc * 64 + fn * 16 + lrow;
    const float bv = bias[col] * alpha;
#pragma unroll
    for (int fm = 0; fm < 4; ++fm) {
      const int row0 = bm0 + wr * 64 + fm * 16 + g * 4;
      if constexpr (MODE == 2) {
        const int b = row0 >> 11, t = row0 & 2047;
        const int bhh = (b << 4) + (col >> 6), d = col & 63;
        u16x4_t pv;
#pragma unroll
        for (int r = 0; r < 4; ++r) pv[r] = f2bf(acc[fm][fn][r] + bv);
        const size_t idx = (((size_t)bhh * 32 + (t >> 6)) * 64 + d) * 64 + (t & 63);
        *(u16x4_t*)((uint16_t*)C + idx) = pv;
      } else if constexpr (MODE == 3) {
        const int b = row0 >> 11, t = row0 & 2047;
        const int bhh = (b << 4) + (col >> 6), d = col & 63;
#pragma unroll
        for (int r = 0; r < 4; ++r)
          ((uint16_t*)C)[((size_t)bhh * 2048 + t + r) * 64 + d] = f2bf(acc[fm][fn][r] + bv);
      } else {
#pragma unroll
        for (int r = 0; r < 4; ++r) {
          const float v = acc[fm][fn][r] + bv;
          if constexpr (MODE == 1)
            ((uint16_t*)C)[(size_t)(row0 + r) * N + col] = f2bf(v);
          else
            ((float*)C)[(size_t)(row0 + r) * N + col] = v;
        }
      }
    }
  }
}

// ----------------------------- flash attention (bf16, HD=64) -----------------------------
// 512 blocks x 512 threads (8 waves, 32 q-rows each -> Q-tile 256). KV tile 64.
// XCD-aware decode: xcd = flat&7 owns bh in [xcd*8, xcd*8+8).
// Kh: [bh][t][64] packed per head; VT: [bh][vt][d][tt] tiled per head -> every staged tile is
// one contiguous 8 KB block (1 KB linear per wave gll16). K+V symmetric double buffer,
// ONE barrier + ONE vmcnt(0) per iteration. Softmax scale pre-folded into Q (exp2 domain).
__global__ __launch_bounds__(512, 4) void attn_kernel(const uint16_t* __restrict__ Q,
                                                      const uint16_t* __restrict__ Kh,
                                                      const uint16_t* __restrict__ VT,
                                                      uint16_t* __restrict__ AO) {
  constexpr int S = 2048, D = 1024;
  __shared__ uint16_t Kb[2][64 * 64];
  __shared__ uint16_t Vb[2][64 * 64];
  __shared__ uint16_t Ps[8][32 * 64];  // per-wave P tile (wave-private)
  char* KbB = (char*)Kb;
  char* VbB = (char*)Vb;
  char* PsB = (char*)Ps;
  const int tid = threadIdx.x;
  const int w = tid >> 6, l = tid & 63;
  const int lrow = l & 15, g = l >> 4;
  const int flat = blockIdx.x;
  const int bh = (flat & 7) * 8 + (flat >> 6);  // XCD = flat&7 owns 8 consecutive bh
  const int qt = (flat >> 3) & 7;
  const int b = bh >> 4, h = bh & 15;
  const int q0 = qt * 256;
  const int srow = l >> 3;
  // within-tile source byte for this lane (contiguous 1 KB per wave, XOR-perm inside 128 B rows)
  const int sofs = (w * 8 + srow) * 128 + (((l & 7) ^ srow) << 4);
  const char* Kg = (const char*)Kh + (size_t)bh * 262144;  // 2048*64*2 B per head
  const char* Vg = (const char*)VT + (size_t)bh * 262144;
  const char* Qb = (const char*)Q;

  // hoist Q fragments (A-operand), already scaled by 0.125*log2e
  bf16x8_t qf[2][2];
#pragma unroll
  for (int fm = 0; fm < 2; ++fm)
#pragma unroll
    for (int kk = 0; kk < 2; ++kk)
      qf[fm][kk] = *(const bf16x8_t*)(Qb + (size_t)(b * S + q0 + w * 32 + fm * 16 + lrow) * (D * 2) +
                                      h * 128 + kk * 64 + g * 16);

  float m_run[8], l_run[8];
#pragma unroll
  for (int i = 0; i < 8; ++i) {
    m_run[i] = -1e30f;
    l_run[i] = 0.f;
  }
  f32x4_t acco[2][4] = {};

  // prologue: stage tile 0 (K and V) into buffer 0
  gll16(Kg + sofs, KbB + w * 1024);
  gll16(Vg + sofs, VbB + w * 1024);

  for (int t = 0; t < 32; ++t) {
    const int cur = (t & 1) * 8192;
    // tile t landed (this wave's parts) + all waves past previous iteration's reads
    asm volatile("s_waitcnt vmcnt(0)\ns_barrier" ::: "memory");

    // prefetch tile t+1 into the other buffer; full compute phase to land
    if (t < 31) {
      const size_t nb = (size_t)(t + 1) * 8192 + sofs;
      gll16(Kg + nb, KbB + (cur ^ 8192) + w * 1024);
      gll16(Vg + nb, VbB + (cur ^ 8192) + w * 1024);
    }

    // QK^T from Kb[cur]
    f32x4_t sacc[2][4] = {};
#pragma unroll
    for (int kk = 0; kk < 2; ++kk)
#pragma unroll
      for (int fn = 0; fn < 4; ++fn) {
        const int kr = fn * 16 + lrow;
        bf16x8_t kf = *(const bf16x8_t*)(KbB + cur + kr * 128 +
                                         ((kk * 64 + g * 16) ^ ((kr & 7) << 4)));
        sacc[0][fn] = MFMA16(qf[0][kk], kf, sacc[0][fn]);
        sacc[1][fn] = MFMA16(qf[1][kk], kf, sacc[1][fn]);
      }

    // online softmax, exp2 domain (scale already folded into Q)
#pragma unroll
    for (int fm = 0; fm < 2; ++fm)
#pragma unroll
      for (int r = 0; r < 4; ++r) {
        float mx = fmaxf(fmaxf(sacc[fm][0][r], sacc[fm][1][r]),
                         fmaxf(sacc[fm][2][r], sacc[fm][3][r]));
#pragma unroll
        for (int dd = 1; dd < 16; dd <<= 1) mx = fmaxf(mx, __shfl_xor(mx, dd));
        const int slot = fm * 4 + r;
        const float mold = m_run[slot];
        const float mnew = fmaxf(mold, mx);
        const float sc = exp2f(mold - mnew);
        m_run[slot] = mnew;
        float rs = 0.f;
#pragma unroll
        for (int fn = 0; fn < 4; ++fn) {
          const float p = exp2f(sacc[fm][fn][r] - mnew);
          sacc[fm][fn][r] = p;
          rs += p;
        }
#pragma unroll
        for (int dd = 1; dd < 16; dd <<= 1) rs += __shfl_xor(rs, dd);
        l_run[slot] = l_run[slot] * sc + rs;
#pragma unroll
        for (int fd = 0; fd < 4; ++fd) acco[fm][fd][r] *= sc;
      }

    // write P (bf16) to wave-private LDS tile [32 r][64 t], swizzled (no barrier needed)
#pragma unroll
    for (int fm = 0; fm < 2; ++fm)
#pragma unroll
      for (int fn = 0; fn < 4; ++fn)
#pragma unroll
        for (int r = 0; r < 4; ++r) {
          const int rloc = fm * 16 + g * 4 + r;
          const int tt = fn * 16 + lrow;
          *(uint16_t*)(PsB + w * 4096 + rloc * 128 + ((2 * tt) ^ ((rloc & 7) << 4))) =
              f2bf(sacc[fm][fn][r]);
        }

    // PV: O[r, d] += P[r, t] * V^T[d, t]   (Vb[cur] synced at this iteration's top barrier)
#pragma unroll
    for (int kk = 0; kk < 2; ++kk) {
      bf16x8_t pf[2];
#pragma unroll
      for (int fm = 0; fm < 2; ++fm) {
        const int pr = fm * 16 + lrow;
        pf[fm] = *(const bf16x8_t*)(PsB + w * 4096 + pr * 128 +
                                    ((kk * 64 + g * 16) ^ ((pr & 7) << 4)));
      }
#pragma unroll
      for (int fd = 0; fd < 4; ++fd) {
        const int vr = fd * 16 + lrow;
        bf16x8_t vf = *(const bf16x8_t*)(VbB + cur + vr * 128 +
                                         ((kk * 64 + g * 16) ^ ((vr & 7) << 4)));
        acco[0][fd] = MFMA16(pf[0], vf, acco[0][fd]);
        acco[1][fd] = MFMA16(pf[1], vf, acco[1][fd]);
      }
    }
  }

  // epilogue: O /= l, write bf16 to AO (row-major [b][s][D] for the output GEMM)
#pragma unroll
  for (int fm = 0; fm < 2; ++fm)
#pragma unroll
    for (int r = 0; r < 4; ++r) {
      const float inv = 1.0f / l_run[fm * 4 + r];
      const size_t row = (size_t)(b * S + q0 + w * 32 + fm * 16 + g * 4 + r);
#pragma unroll
      for (int fd = 0; fd < 4; ++fd)
        AO[row * D + h * 64 + fd * 16 + lrow] = f2bf(acco[fm][fd][r] * inv);
    }
}

// ----------------------------- launch -----------------------------
extern "C" void kernel_launch(void* const* d_in, const int* in_sizes, int n_in,
                              void* d_out, int out_size, void* d_ws, size_t ws_size,
                              hipStream_t stream) {
  const float* q_in = (const float*)d_in[0];
  const float* k_in = (const float*)d_in[1];
  const float* v_in = (const float*)d_in[2];
  const float* Wq = (const float*)d_in[3];
  const float* bq = (const float*)d_in[4];
  const float* Wk = (const float*)d_in[5];
  const float* bk = (const float*)d_in[6];
  const float* Wv = (const float*)d_in[7];
  const float* bv = (const float*)d_in[8];
  const float* Wo = (const float*)d_in[9];
  const float* bo = (const float*)d_in[10];

  const size_t MD = (size_t)8192 * 1024;
  const size_t DD = (size_t)1024 * 1024;
  uint16_t* Xq = (uint16_t*)d_ws;
  uint16_t* Xk = Xq + MD;
  uint16_t* Xv = Xk + MD;
  uint16_t* Wqb = Xv + MD;
  uint16_t* Wkb = Wqb + DD;
  uint16_t* Wvb = Wkb + DD;
  uint16_t* Wob = Wvb + DD;
  uint16_t* Qp = Wob + DD;
  uint16_t* Kp = Qp + MD;
  uint16_t* VTp = Kp + MD;
  uint16_t* AO = Xq;  // reuse Xq: consumed by Q projection before attn writes

  const float QSCALE = 0.125f * 1.44269504088896f;  // 1/sqrt(64) * log2(e)

  dim3 cb(256);
  cvt_kernel<<<4096, cb, 0, stream>>>(q_in, Xq, 1048576, 1.0f);
  cvt_kernel<<<4096, cb, 0, stream>>>(k_in, Xk, 1048576, 1.0f);
  cvt_kernel<<<4096, cb, 0, stream>>>(v_in, Xv, 1048576, 1.0f);
  cvt_kernel<<<512, cb, 0, stream>>>(Wq, Wqb, 131072, QSCALE);
  cvt_kernel<<<512, cb, 0, stream>>>(Wk, Wkb, 131072, 1.0f);
  cvt_kernel<<<512, cb, 0, stream>>>(Wv, Wvb, 131072, 1.0f);
  cvt_kernel<<<512, cb, 0, stream>>>(Wo, Wob, 131072, 1.0f);

  dim3 gg(8, 64), gb(256);
  gemm_bt_kernel<1><<<gg, gb, 0, stream>>>(Xq, Wqb, bq, Qp, QSCALE);
  gemm_bt_kernel<3><<<gg, gb, 0, stream>>>(Xk, Wkb, bk, Kp, 1.0f);
  gemm_bt_kernel<2><<<gg, gb, 0, stream>>>(Xv, Wvb, bv, VTp, 1.0f);

  attn_kernel<<<512, 512, 0, stream>>>(Qp, Kp, VTp, AO);

  gemm_bt_kernel<0><<<gg, gb, 0, stream>>>(AO, Wob, bo, d_out, 1.0f);
}